// Round 9
// baseline (160.630 us; speedup 1.0000x reference)
//
#include <hip/hip_runtime.h>

// (B, S, H) = (8, 2048, 1024), fp32.
// Degenerate math: scores == 1/S exactly (softmax of a constant vector);
// context[b,h] == mean_s enc[b,s,h]; decoder_state cancels entirely.
// Lessons: R2 — grid.sync() ~200us; R3 — contended atomics lose; R4 — wide
//   finalize; R5 — load depth > occupancy; R6 — SGB null (19.06us best);
//   R7 — moving the 4 MiB partial path onto device-coherent scalar atomics
//   destroyed BW (1.1 TB/s). R8(now): R6 hot path UNCHANGED (cached float4),
//   single dispatch via release-flag + spin: only flags are coherent.
#define BB 8
#define SS 2048
#define HH 1024
#define NCHUNK 128
#define CHUNK (SS / NCHUNK)            // 16
#define NBLK (BB * NCHUNK)             // 1024
#define FLAGS_OFF ((size_t)NBLK * HH)  // float offset of flag area in ws

__global__ void __launch_bounds__(256)
att_onepass_kernel(const float* __restrict__ enc, float* __restrict__ ws,
                   float* __restrict__ out) {
    const int g = blockIdx.x;
    const int b = g >> 7;            // / NCHUNK
    const int c = g & (NCHUNK - 1);
    const int t = threadIdx.x;
    const float inv = 1.0f / SS;
    unsigned int* flags = (unsigned int*)(ws + FLAGS_OFF);
    const unsigned int magic = __float_as_uint(enc[0]) ^ 0xC001CAFEu;

    // ---- produce (identical to R6): 16-deep float4 MLP, cached stores ----
    {
        const float4* p =
            (const float4*)(enc + ((size_t)b * SS + (size_t)c * CHUNK) * HH) + t;
        float4 v[CHUNK];
        #pragma unroll
        for (int s = 0; s < CHUNK; ++s) v[s] = p[(size_t)s * (HH / 4)];
        __builtin_amdgcn_sched_group_barrier(0x20, 16, 0);  // 16x VMEM_READ
        __builtin_amdgcn_sched_group_barrier(0x02, 64, 0);  // then VALU
        #pragma unroll
        for (int stride = CHUNK / 2; stride > 0; stride >>= 1) {
            #pragma unroll
            for (int s = 0; s < stride; ++s) {
                v[s].x += v[s + stride].x;
                v[s].y += v[s + stride].y;
                v[s].z += v[s + stride].z;
                v[s].w += v[s + stride].w;
            }
        }
        ((float4*)(ws + (size_t)g * HH))[t] = v[0];
    }

    // scores: 16 per block, independent
    if (t < 16) out[BB * HH + g * 16 + t] = inv;

    __syncthreads();  // all partial stores issued (vmcnt drained at barrier)
    if (t == 0)
        __hip_atomic_store(&flags[g], magic, __ATOMIC_RELEASE,
                           __HIP_MEMORY_SCOPE_AGENT);  // L2 writeback + flag

    // ---- consumer role: 16 blocks per batch (c multiple of 8) ----
    if ((c & 7) != 0) return;
    const int hbase = (c >> 3) * 64;   // 16 slices x 64 h

    if (t < NCHUNK) {
        while (__hip_atomic_load(&flags[(b << 7) + t], __ATOMIC_RELAXED,
                                 __HIP_MEMORY_SCOPE_AGENT) != magic)
            __builtin_amdgcn_s_sleep(2);
    }
    __threadfence();   // acquire side: invalidate L1/L2 before data reads
    __syncthreads();

    // finalize (R4/R6 pattern): wave cq sums 32 chunk-partials, cached loads
    const int hl = t & 63;
    const int cq = t >> 6;             // 0..3
    const float* q = ws + ((size_t)((b << 7) + cq * 32)) * HH + hbase + hl;
    float s = 0.f;
    #pragma unroll 8
    for (int i = 0; i < 32; ++i) s += q[(size_t)i * HH];

    __shared__ float lds[4][64];
    lds[cq][hl] = s;
    __syncthreads();
    if (t < 64)
        out[b * HH + hbase + t] =
            (lds[0][t] + lds[1][t] + lds[2][t] + lds[3][t]) * inv;
}

// Fallback (workspace too small): two-kernel path from R6.
__global__ void __launch_bounds__(256)
att_partial_kernel(const float* __restrict__ enc, float* __restrict__ partial) {
    int blk = blockIdx.x;
    int b = blk >> 7;
    int c = blk & (NCHUNK - 1);
    int t = threadIdx.x;
    const float4* p =
        (const float4*)(enc + ((size_t)b * SS + (size_t)c * CHUNK) * HH) + t;
    float4 v[CHUNK];
    #pragma unroll
    for (int s = 0; s < CHUNK; ++s) v[s] = p[(size_t)s * (HH / 4)];
    #pragma unroll
    for (int stride = CHUNK / 2; stride > 0; stride >>= 1) {
        #pragma unroll
        for (int s = 0; s < stride; ++s) {
            v[s].x += v[s + stride].x;
            v[s].y += v[s + stride].y;
            v[s].z += v[s + stride].z;
            v[s].w += v[s + stride].w;
        }
    }
    ((float4*)(partial + ((size_t)b * NCHUNK + c) * HH))[t] = v[0];
}

__global__ void __launch_bounds__(256)
att_finalize_kernel(const float* __restrict__ partial, float* __restrict__ out) {
    const int blk = blockIdx.x;
    const int b = blk >> 4;
    const int hbase = (blk & 15) * 64;
    const int t = threadIdx.x;
    const int hl = t & 63;
    const int cq = t >> 6;
    const float* p = partial + ((size_t)(b * NCHUNK + cq * 32)) * HH + hbase + hl;
    float acc = 0.f;
    #pragma unroll 8
    for (int c = 0; c < 32; ++c) acc += p[(size_t)c * HH];
    const float inv = 1.0f / SS;
    if (t >= 64 && t < 192) out[BB * HH + blk * 128 + (t - 64)] = inv;
    __shared__ float lds[4][64];
    lds[cq][hl] = acc;
    __syncthreads();
    if (t < 64) {
        float s = lds[0][t] + lds[1][t] + lds[2][t] + lds[3][t];
        out[b * HH + hbase + t] = s * inv;
    }
}

extern "C" void kernel_launch(void* const* d_in, const int* in_sizes, int n_in,
                              void* d_out, int out_size, void* d_ws, size_t ws_size,
                              hipStream_t stream) {
    const float* enc = (const float*)d_in[1];  // encoder_outputs (B,S,H)
    float* out = (float*)d_out;                // [context (B*H) | scores (B*S)]

    const size_t need = (FLAGS_OFF + NBLK) * sizeof(float);  // 4 MiB + 4 KiB
    if (d_ws != nullptr && ws_size >= need) {
        att_onepass_kernel<<<NBLK, 256, 0, stream>>>(enc, (float*)d_ws, out);
    } else if (d_ws != nullptr &&
               ws_size >= (size_t)NBLK * HH * sizeof(float)) {
        float* partial = (float*)d_ws;
        att_partial_kernel<<<NBLK, 256, 0, stream>>>(enc, partial);
        att_finalize_kernel<<<128, 256, 0, stream>>>(partial, out);
    }
}

// Round 10
// 19.341 us; speedup vs baseline: 8.3053x; 8.3053x over previous
//
#include <hip/hip_runtime.h>

// (B, S, H) = (8, 2048, 1024), fp32.
// Degenerate math: scores == 1/S exactly (softmax of a constant vector);
// context[b,h] == mean_s enc[b,s,h]; decoder_state cancels entirely.
// Lessons: R2 — grid.sync() ~200us; R3 — contended atomics lose; R4 — wide
//   finalize; R5 — load depth > occupancy; R6 — SGB alone null (19.06us);
//   R7/R8 — single-dispatch coherence (atomics / release-flag+spin) costs
//   10x the dispatch it saves (per-block L2 writebacks). 2-dispatch is
//   structurally optimal. R9: VGPR_Count=36 proves compiler recycled regs
//   (~5-6 loads in flight, SGB cosmetic). launch_bounds(256,4) raises the
//   VGPR budget to 128 so all 16 float4 loads stay live.
#define BB 8
#define SS 2048
#define HH 1024
#define NCHUNK 128           // S-chunks per batch
#define CHUNK (SS / NCHUNK)  // 16 rows per block
#define NBLK (BB * NCHUNK)   // 1024 blocks

// Kernel A: block (b,c) sums its 16-row chunk; thread t owns float4 column
// h=4t..4t+3; 16 independent global_load_dwordx4 kept live in VGPRs
// (launch_bounds(256,4): 128-VGPR budget), issued before the VALU tree.
__global__ void __launch_bounds__(256, 4)
att_partial_kernel(const float* __restrict__ enc, float* __restrict__ partial) {
    int blk = blockIdx.x;
    int b = blk >> 7;          // / NCHUNK
    int c = blk & (NCHUNK - 1);
    int t = threadIdx.x;
    const float4* p =
        (const float4*)(enc + ((size_t)b * SS + (size_t)c * CHUNK) * HH) + t;
    float4 v[CHUNK];
    #pragma unroll
    for (int s = 0; s < CHUNK; ++s) v[s] = p[(size_t)s * (HH / 4)];
    // emit all 16 VMEM reads first, then the VALU tree
    __builtin_amdgcn_sched_group_barrier(0x20, 16, 0);  // 16x VMEM_READ
    __builtin_amdgcn_sched_group_barrier(0x02, 64, 0);  // then VALU
    #pragma unroll
    for (int stride = CHUNK / 2; stride > 0; stride >>= 1) {
        #pragma unroll
        for (int s = 0; s < stride; ++s) {
            v[s].x += v[s + stride].x;
            v[s].y += v[s + stride].y;
            v[s].z += v[s + stride].z;
            v[s].w += v[s + stride].w;
        }
    }
    ((float4*)(partial + ((size_t)b * NCHUNK + c) * HH))[t] = v[0];
}

// Kernel B (R4/R6, proven): 128 blocks x 256 threads. Block = (b, 64-wide h
// slice). Wave cq sums c = cq*32..cq*32+31 (coalesced 256 B/wave reads),
// LDS[4][64] cross-wave combine; fills 128 scores per block.
__global__ void __launch_bounds__(256)
att_finalize_kernel(const float* __restrict__ partial, float* __restrict__ out) {
    const int blk = blockIdx.x;        // 0..127
    const int b = blk >> 4;            // / 16
    const int hbase = (blk & 15) * 64;
    const int t = threadIdx.x;
    const int hl = t & 63;
    const int cq = t >> 6;             // 0..3

    const float* p = partial + ((size_t)(b * NCHUNK + cq * 32)) * HH + hbase + hl;
    float acc = 0.f;
    #pragma unroll 8
    for (int c = 0; c < 32; ++c) acc += p[(size_t)c * HH];

    const float inv = 1.0f / SS;
    if (t >= 64 && t < 192) {
        out[BB * HH + blk * 128 + (t - 64)] = inv;
    }

    __shared__ float lds[4][64];
    lds[cq][hl] = acc;
    __syncthreads();
    if (t < 64) {
        float s = lds[0][t] + lds[1][t] + lds[2][t] + lds[3][t];
        out[b * HH + hbase + t] = s * inv;
    }
}

// Fallback (workspace too small): direct full-column sums.
__global__ void __launch_bounds__(256)
att_direct_kernel(const float* __restrict__ enc, float* __restrict__ out) {
    int tid = blockIdx.x * blockDim.x + threadIdx.x;
    if (tid < BB * HH) {
        int b = tid >> 10;
        int h = tid & (HH - 1);
        const float* p = enc + (size_t)b * SS * HH + h;
        float acc = 0.f;
        for (int s = 0; s < SS; ++s) acc += p[(size_t)s * HH];
        out[tid] = acc * (1.0f / SS);
    } else if (tid < BB * HH + BB * SS) {
        out[tid] = 1.0f / SS;
    }
}

extern "C" void kernel_launch(void* const* d_in, const int* in_sizes, int n_in,
                              void* d_out, int out_size, void* d_ws, size_t ws_size,
                              hipStream_t stream) {
    const float* enc = (const float*)d_in[1];  // encoder_outputs (B,S,H)
    float* out = (float*)d_out;                // [context (B*H) | scores (B*S)]

    const size_t part_bytes = (size_t)BB * NCHUNK * HH * sizeof(float);  // 4 MiB
    if (d_ws != nullptr && ws_size >= part_bytes) {
        float* partial = (float*)d_ws;
        att_partial_kernel<<<NBLK, 256, 0, stream>>>(enc, partial);
        att_finalize_kernel<<<128, 256, 0, stream>>>(partial, out);
    } else {
        const int total_out = BB * HH + BB * SS;
        att_direct_kernel<<<(total_out + 255) / 256, 256, 0, stream>>>(enc, out);
    }
}

// Round 11
// 17.387 us; speedup vs baseline: 9.2386x; 1.1124x over previous
//
#include <hip/hip_runtime.h>

// (B, S, H) = (8, 2048, 1024), fp32.
// Degenerate math: scores == 1/S exactly (softmax of a constant vector);
// context[b,h] == mean_s enc[b,s,h]; decoder_state cancels entirely.
// Lessons: R2 — grid.sync() ~200us; R3 — contended atomics; R4 — wide
//   finalize; R5 — shallower+more blocks regressed; R6 — SGB null (19.06);
//   R7/R8 — single-dispatch coherence 10x worse; R9 — VGPR budget null.
//   Phase A plateau ~5 TB/s across 3 configs. R10: fewer/deeper blocks —
//   512 blocks x 32-row chunks, 4x8-deep unrolled passes (compiler can
//   software-pipeline loads across passes = continuous issue, like the
//   fill kernel that hits 6.8 TB/s at 2.6 waves/CU). Partials 4->2 MiB.
#define BB 8
#define SS 2048
#define HH 1024
#define NCHUNK 64            // S-chunks per batch
#define CHUNK (SS / NCHUNK)  // 32 rows per block
#define NBLK (BB * NCHUNK)   // 512 blocks

// Kernel A: block g=(b,c) sums its 32-row chunk; thread t owns float4 column
// h=4t..4t+3. 4 passes x 8 independent loads, unrolled -> 32-load pipeline
// window; launch_bounds(256,4) gives a 128-VGPR budget for in-flight data.
__global__ void __launch_bounds__(256, 4)
att_partial_kernel(const float* __restrict__ enc, float* __restrict__ partial) {
    const int g = blockIdx.x;
    const int b = g >> 6;            // / NCHUNK
    const int c = g & (NCHUNK - 1);
    const int t = threadIdx.x;
    const float4* p =
        (const float4*)(enc + ((size_t)b * SS + (size_t)c * CHUNK) * HH) + t;

    float4 acc = make_float4(0.f, 0.f, 0.f, 0.f);
    #pragma unroll
    for (int pass = 0; pass < 4; ++pass) {
        float4 v[8];
        #pragma unroll
        for (int s = 0; s < 8; ++s)
            v[s] = p[(size_t)(pass * 8 + s) * (HH / 4)];
        #pragma unroll
        for (int st = 4; st > 0; st >>= 1) {
            #pragma unroll
            for (int s = 0; s < st; ++s) {
                v[s].x += v[s + st].x; v[s].y += v[s + st].y;
                v[s].z += v[s + st].z; v[s].w += v[s + st].w;
            }
        }
        acc.x += v[0].x; acc.y += v[0].y; acc.z += v[0].z; acc.w += v[0].w;
    }
    ((float4*)(partial + (size_t)g * HH))[t] = acc;  // g == b*NCHUNK + c
}

// Kernel B: 128 blocks x 256 threads. Block = (b, 64-wide h slice); wave cq
// sums chunks c = cq*16..cq*16+15 (coalesced 256 B/wave reads), LDS[4][64]
// cross-wave combine; fills 128 scores per block.
__global__ void __launch_bounds__(256)
att_finalize_kernel(const float* __restrict__ partial, float* __restrict__ out) {
    const int blk = blockIdx.x;        // 0..127
    const int b = blk >> 4;            // / 16
    const int hbase = (blk & 15) * 64;
    const int t = threadIdx.x;
    const int hl = t & 63;
    const int cq = t >> 6;             // 0..3

    const float* p =
        partial + ((size_t)(b * NCHUNK + cq * 16)) * HH + hbase + hl;
    float acc = 0.f;
    #pragma unroll
    for (int c = 0; c < 16; ++c) acc += p[(size_t)c * HH];

    const float inv = 1.0f / SS;
    if (t >= 64 && t < 192) {
        out[BB * HH + blk * 128 + (t - 64)] = inv;
    }

    __shared__ float lds[4][64];
    lds[cq][hl] = acc;
    __syncthreads();
    if (t < 64) {
        float s = lds[0][t] + lds[1][t] + lds[2][t] + lds[3][t];
        out[b * HH + hbase + t] = s * inv;
    }
}

// Fallback (workspace too small): direct full-column sums.
__global__ void __launch_bounds__(256)
att_direct_kernel(const float* __restrict__ enc, float* __restrict__ out) {
    int tid = blockIdx.x * blockDim.x + threadIdx.x;
    if (tid < BB * HH) {
        int b = tid >> 10;
        int h = tid & (HH - 1);
        const float* p = enc + (size_t)b * SS * HH + h;
        float acc = 0.f;
        for (int s = 0; s < SS; ++s) acc += p[(size_t)s * HH];
        out[tid] = acc * (1.0f / SS);
    } else if (tid < BB * HH + BB * SS) {
        out[tid] = 1.0f / SS;
    }
}

extern "C" void kernel_launch(void* const* d_in, const int* in_sizes, int n_in,
                              void* d_out, int out_size, void* d_ws, size_t ws_size,
                              hipStream_t stream) {
    const float* enc = (const float*)d_in[1];  // encoder_outputs (B,S,H)
    float* out = (float*)d_out;                // [context (B*H) | scores (B*S)]

    const size_t part_bytes = (size_t)NBLK * HH * sizeof(float);  // 2 MiB
    if (d_ws != nullptr && ws_size >= part_bytes) {
        float* partial = (float*)d_ws;
        att_partial_kernel<<<NBLK, 256, 0, stream>>>(enc, partial);
        att_finalize_kernel<<<128, 256, 0, stream>>>(partial, out);
    } else {
        const int total_out = BB * HH + BB * SS;
        att_direct_kernel<<<(total_out + 255) / 256, 256, 0, stream>>>(enc, out);
    }
}